// Round 3
// baseline (550.987 us; speedup 1.0000x reference)
//
#include <hip/hip_runtime.h>
#include <math.h>

// 2-layer ReLU RNN, B=256, T=1000 (input 800 + zero pad), H=128, F=5.
// R18 = R17 with the matvec OOB bug fixed (hv[8] -> hv[16]: R17 loaded only
// 64 of 128 h elements, hp2/hp3 indexed hv[8..15] out of bounds -> UB).
// Structure: 8 waves (512 thr), lane-owns-row:
//   wv0,1 = h0 engine (Whh0 rows 0-63 / 64-127 + x-dot)
//   wv2,3 = A engine  (Wih1)      wv4,5 = h1 engine (Whh1)
//   wv6   = y-dots every 16 steps wv7   = idle (barriers only)
// Each lane owns ONE output row: 64 fdot2 over 128 cols, weights = 64 VGPRs,
// NO cross-lane reduce (no DPP tree, no XOR maps, no writer masks). h read
// as 16x ds_read_b128 all-lane broadcast (conflict-free). 2 waves/SIMD give
// TLP to hide LDS + chain latency. Ring rows padded +8 h16 (stride 272B)
// so the y-wave's 16-row burst spreads across banks (R16: 613K conflicts).
// Same pipeline skew / double-buffer / ring schedule as R15/R16 (verified).

#define TT    1000
#define TIN   800
#define HD    128
#define NF    5
#define BATCH 256
#define RS    (HD + 8)      // ring row stride in h16 (272B: breaks bank alias)

typedef _Float16 h16x2 __attribute__((ext_vector_type(2)));
typedef _Float16 h16x8 __attribute__((ext_vector_type(8)));

template<int CTRL>
__device__ __forceinline__ float dpp_mov(float v) {
    union { float f; int i; } u, r;
    u.f = v;
    r.i = __builtin_amdgcn_update_dpp(0, u.i, CTRL, 0xF, 0xF, true);
    return r.f;
}

__global__ __launch_bounds__(512, 2) void rnn_row(
    const float* __restrict__ x,        // [256,800,5]
    const float* __restrict__ h_state,  // [2,256,128]
    const float* __restrict__ w_ih0,    // [128,5]
    const float* __restrict__ w_hh0,    // [128,128]
    const float* __restrict__ b_ih0,    // [128]
    const float* __restrict__ b_hh0,    // [128]
    const float* __restrict__ w_ih1,    // [128,128]
    const float* __restrict__ w_hh1,    // [128,128]
    const float* __restrict__ b_ih1,    // [128]
    const float* __restrict__ b_hh1,    // [128]
    const float* __restrict__ w_out,    // [1,128]
    const float* __restrict__ b_out,    // [1]
    float* __restrict__ out)            // [204800 y] ++ [65536 final states]
{
    __shared__ __align__(16) _Float16 x_h[TIN * 8];      // fp16, 12.8 KB
    __shared__ __align__(16) _Float16 h0h[2][HD];
    __shared__ __align__(16) float A_f[2][HD];           // fp32 pre-act
    __shared__ __align__(16) _Float16 ring[32][RS];      // h1 state+history
    __shared__ float y_lds[TIN];

    const int tid  = threadIdx.x;
    const int bb   = blockIdx.x;
    const int wv   = tid >> 6;          // wave id 0..7
    const int lane = tid & 63;
    const int eng  = wv >> 1;           // 0:h0  1:A  2:h1  3:y/idle
    const int half = wv & 1;
    const int row  = half * 64 + lane;  // this lane's output row (engines)

    // ---- stage x[bb] into LDS (fp16, stride 8, pads zero) ----
    for (int i = tid; i < TIN * 8; i += 512) x_h[i] = (_Float16)0.f;
    __syncthreads();
    for (int i = tid; i < TIN * NF; i += 512) {
        int t = i / 5, f = i - 5 * t;
        x_h[t * 8 + f] = (_Float16)x[bb * (TIN * NF) + i];
    }
    if (tid < HD) {
        h0h[0][tid]   = (_Float16)h_state[bb * HD + tid];
        ring[31][tid] = (_Float16)h_state[BATCH * HD + bb * HD + tid];  // h1[-1]
    }

    // ---- weights: one full row per lane, fp16 pairs (64 VGPRs) ----
    h16x2 wp[64];
    if (eng < 3) {
        const float* Wsrc = (eng == 0) ? w_hh0 : ((eng == 1) ? w_ih1 : w_hh1);
        const float* rp = Wsrc + row * HD;
        #pragma unroll
        for (int t = 0; t < 64; ++t) {
            h16x2 w2 = { (_Float16)rp[2 * t], (_Float16)rp[2 * t + 1] };
            wp[t] = w2;
        }
    }

    h16x2 wx[3];                        // eng0: Wih0 row (5 + 1 zero pad)
    h16x2 wo[16];                       // wv6: wout cols c*32..+31
    float bias = 0.f;
    if (eng == 0) {
        wx[0][0] = (_Float16)w_ih0[row * NF + 0];
        wx[0][1] = (_Float16)w_ih0[row * NF + 1];
        wx[1][0] = (_Float16)w_ih0[row * NF + 2];
        wx[1][1] = (_Float16)w_ih0[row * NF + 3];
        wx[2][0] = (_Float16)w_ih0[row * NF + 4];
        wx[2][1] = (_Float16)0.f;
        bias = b_ih0[row] + b_hh0[row];
    } else if (eng == 2) {
        bias = b_ih1[row] + b_hh1[row];
    } else if (wv == 6) {
        const int c = lane & 3;
        #pragma unroll
        for (int t = 0; t < 16; ++t) {
            h16x2 w2 = { (_Float16)w_out[c * 32 + 2 * t],
                         (_Float16)w_out[c * 32 + 2 * t + 1] };
            wo[t] = w2;
        }
    }
    const float bout = b_out[0];

    float hfin = 0.f;

    __syncthreads();

    // Full-row matvec: 16 broadcast ds_read_b128 + 64 fdot2 in 4 indep chains.
    auto matvec = [&](const _Float16* hbuf) -> float {
        h16x8 hv[16];
        #pragma unroll
        for (int u2 = 0; u2 < 16; ++u2)
            hv[u2] = *(const h16x8*)(hbuf + 8 * u2);     // all-lane broadcast
        float acc0 = 0.f, acc1 = 0.f, acc2 = 0.f, acc3 = 0.f;
        #pragma unroll
        for (int t = 0; t < 16; ++t) {
            h16x2 hp0 = { hv[(t)      >> 2][2 * (t & 3)], hv[(t)      >> 2][2 * (t & 3) + 1] };
            h16x2 hp1 = { hv[(t + 16) >> 2][2 * (t & 3)], hv[(t + 16) >> 2][2 * (t & 3) + 1] };
            h16x2 hp2 = { hv[(t + 32) >> 2][2 * (t & 3)], hv[(t + 32) >> 2][2 * (t & 3) + 1] };
            h16x2 hp3 = { hv[(t + 48) >> 2][2 * (t & 3)], hv[(t + 48) >> 2][2 * (t & 3) + 1] };
            acc0 = __builtin_amdgcn_fdot2(wp[t],      hp0, acc0, false);
            acc1 = __builtin_amdgcn_fdot2(wp[t + 16], hp1, acc1, false);
            acc2 = __builtin_amdgcn_fdot2(wp[t + 32], hp2, acc2, false);
            acc3 = __builtin_amdgcn_fdot2(wp[t + 48], hp3, acc3, false);
        }
        return (acc0 + acc1) + (acc2 + acc3);
    };

    #pragma unroll 2
    for (int s = 0; s < TT + 2; ++s) {
        const int p = s & 1;
        const int q = p ^ 1;

        if (eng == 0) {
            // h0[s] = relu(Whh0.h0[s-1] + Wih0.x[s] + b)
            if (s < TT) {
                float v = matvec(h0h[p]) + bias;
                if (s < TIN) {      // uniform branch
                    h16x8 xv = *(const h16x8*)(&x_h[s * 8]);
                    h16x2 xp0 = { xv[0], xv[1] };
                    h16x2 xp1 = { xv[2], xv[3] };
                    h16x2 xp2 = { xv[4], xv[5] };   // slot 5 is zero pad
                    float xc = __builtin_amdgcn_fdot2(wx[2], xp2, 0.f, false);
                    xc = __builtin_amdgcn_fdot2(wx[1], xp1, xc, false);
                    xc = __builtin_amdgcn_fdot2(wx[0], xp0, xc, false);
                    v += xc;
                }
                v = fmaxf(v, 0.f);
                h0h[q][row] = (_Float16)v;
                if (s == TT - 1) hfin = v;
            }
        } else if (eng == 1) {
            // A[s-1] = Wih1 . h0[s-1]  (fp32)
            if (s <= TT) {
                A_f[q][row] = matvec(h0h[p]);
            }
        } else if (eng == 2) {
            // h1[s-2] = relu(A[s-2] + Whh1.h1[s-3] + b); h1 lives in ring
            if (s >= 2) {
                const int u = s - 2;
                float v = matvec(&ring[(u + 31) & 31][0]);
                v = fmaxf(v + bias + A_f[p][row], 0.f);
                ring[u & 31][row] = (_Float16)v;
                if (u == TT - 1) hfin = v;
            }
        } else if (wv == 6) {
            // y-dots every 16 steps: 16 slots x 4 lanes, DPP-only reduce
            if (s >= 18 && s <= 818 && ((s - 2) & 15) == 0) {
                const int slot = lane >> 2;
                const int c    = lane & 3;
                const int u    = (s - 33) + slot;
                if (u >= 0 && u < TIN) {
                    const _Float16* rb = &ring[u & 31][0] + c * 32;
                    float z = 0.f;
                    #pragma unroll
                    for (int u2 = 0; u2 < 4; ++u2) {
                        h16x8 hv = *(const h16x8*)(rb + 8 * u2);
                        h16x2 hp0 = { hv[0], hv[1] };
                        h16x2 hp1 = { hv[2], hv[3] };
                        h16x2 hp2 = { hv[4], hv[5] };
                        h16x2 hp3 = { hv[6], hv[7] };
                        z = __builtin_amdgcn_fdot2(wo[4 * u2 + 0], hp0, z, false);
                        z = __builtin_amdgcn_fdot2(wo[4 * u2 + 1], hp1, z, false);
                        z = __builtin_amdgcn_fdot2(wo[4 * u2 + 2], hp2, z, false);
                        z = __builtin_amdgcn_fdot2(wo[4 * u2 + 3], hp3, z, false);
                    }
                    z += dpp_mov<0xB1>(z);    // xor1 (within quad = same slot)
                    z += dpp_mov<0x4E>(z);    // xor2
                    if (c == 0) y_lds[u] = 1.f / (1.f + expf(-(z + bout)));
                }
            }
        }
        __syncthreads();
    }

    // ---- epilogue: single global dump ----
    for (int i = tid; i < TIN; i += 512)
        out[bb * TIN + i] = y_lds[i];
    if (wv < 2)
        out[TIN * BATCH + bb * HD + row] = hfin;
    else if (eng == 2)
        out[TIN * BATCH + BATCH * HD + bb * HD + row] = hfin;
}

extern "C" void kernel_launch(void* const* d_in, const int* in_sizes, int n_in,
                              void* d_out, int out_size, void* d_ws, size_t ws_size,
                              hipStream_t stream) {
    (void)in_sizes; (void)n_in; (void)d_ws; (void)ws_size; (void)out_size;
    rnn_row<<<dim3(BATCH), dim3(512), 0, stream>>>(
        (const float*)d_in[0],  (const float*)d_in[1],
        (const float*)d_in[2],  (const float*)d_in[3],
        (const float*)d_in[4],  (const float*)d_in[5],
        (const float*)d_in[6],  (const float*)d_in[7],
        (const float*)d_in[8],  (const float*)d_in[9],
        (const float*)d_in[10], (const float*)d_in[11],
        (float*)d_out);
}

// Round 5
// 429.375 us; speedup vs baseline: 1.2832x; 1.2832x over previous
//
#include <hip/hip_runtime.h>
#include <math.h>

// 2-layer ReLU RNN, B=256, T=1000 (input 800 + zero pad), H=128, F=5.
// R20 = R19 (infra-failed, audited clean) + weight-store UNION:
// wp (engines, 64 VGPR) / af (A-MFMA, 64 VGPR) / wo (y, 16 VGPR) are live on
// DISJOINT wave roles but static regalloc can't overlap distinct arrays ->
// ~150 VGPR demand -> spill at the 128 cap (R16 failure mode). Union forces
// them into the same 64 registers.
// Structure (512 thr, 8 waves; SIMD pairing wv{i, i+4}):
//   wv0,1 = h0 engine: tiled matvec, 16 row-groups x 4 col-chunks (32 cols =
//           64B/lane, 4 ds_read_b128), 4 rows/lane, XOR row map
//           g=2*(c&1)+((c>>1)&1), 2-level DPP tree (0xB1, 0x4E).
//   wv2,3 = h1 engine, skew 20, reads A_f ring.
//   wv4,5 = A-engine: A[u]=Wih1.h0[u] has no recurrence -> batched every 16
//           steps as 128x128x16 GEMM on mfma_f32_16x16x32_f16 (~2 inst/step
//           vs 86). Serial per-step work: 3 matvecs -> 2.
//   wv6   = y burst at s=37+16k;  wv7 idle.
// All ring read/write sets verified disjoint mod 32 (see R19 notes).
// History: issue/SIMD is NOT the floor (R15 694cyc issue beat R18's 483);
// LDS return (R18: 256B/lane) + 3-engine serial path was.

#define TT    1000
#define TIN   800
#define HD    128
#define NF    5
#define BATCH 256
#define RS    136           // h16 ring row stride (272B = 17x16B, aligned)
#define AS    132           // f32 A-ring row stride (528B = 33x16B, aligned)
#define SK1   20            // h1 skew: h1[u] computed at step u+20
#define NSTEP (TT + SK1)    // 1020 steps

typedef _Float16 h16x2 __attribute__((ext_vector_type(2)));
typedef _Float16 h16x8 __attribute__((ext_vector_type(8)));
typedef float    f32x4 __attribute__((ext_vector_type(4)));

template<int CTRL>
__device__ __forceinline__ float dpp_mov(float v) {
    union { float f; int i; } u, r;
    u.f = v;
    r.i = __builtin_amdgcn_update_dpp(0, u.i, CTRL, 0xF, 0xF, true);
    return r.f;
}

__global__ __launch_bounds__(512, 2) void rnn_dec(
    const float* __restrict__ x,        // [256,800,5]
    const float* __restrict__ h_state,  // [2,256,128]
    const float* __restrict__ w_ih0,    // [128,5]
    const float* __restrict__ w_hh0,    // [128,128]
    const float* __restrict__ b_ih0,    // [128]
    const float* __restrict__ b_hh0,    // [128]
    const float* __restrict__ w_ih1,    // [128,128]
    const float* __restrict__ w_hh1,    // [128,128]
    const float* __restrict__ b_ih1,    // [128]
    const float* __restrict__ b_hh1,    // [128]
    const float* __restrict__ w_out,    // [1,128]
    const float* __restrict__ b_out,    // [1]
    float* __restrict__ out)            // [204800 y] ++ [65536 final states]
{
    __shared__ __align__(16) _Float16 x_h[TIN * 8];      // 12.8 KB
    __shared__ __align__(16) _Float16 ring0[32][RS];     // h0 history, 8.7 KB
    __shared__ __align__(16) _Float16 ring1[32][RS];     // h1 history, 8.7 KB
    __shared__ __align__(16) float    A_f[32][AS];       // Wih1.h0 ring, 16.9 KB
    __shared__ float y_lds[TIN];                          // 3.2 KB

    const int tid  = threadIdx.x;
    const int bb   = blockIdx.x;
    const int wv   = tid >> 6;          // wave id 0..7
    const int lane = tid & 63;

    // ---- stage x[bb] into LDS (fp16, stride 8, pads zero) ----
    for (int i = tid; i < TIN * 8; i += 512) x_h[i] = (_Float16)0.f;
    __syncthreads();
    for (int i = tid; i < TIN * NF; i += 512) {
        int t = i / 5, f = i - 5 * t;
        x_h[t * 8 + f] = (_Float16)x[bb * (TIN * NF) + i];
    }
    if (tid < HD) {
        ring0[31][tid] = (_Float16)h_state[bb * HD + tid];              // h0[-1]
        ring1[31][tid] = (_Float16)h_state[BATCH * HD + bb * HD + tid]; // h1[-1]
    }

    // ---- h-engine lane geometry (wv 0..3) ----
    const int c    = lane & 3;                      // col chunk (32 cols)
    const int rg   = lane >> 2;                     // row group (4 rows)
    const int g    = 2 * (c & 1) + ((c >> 1) & 1);  // XOR row map (2-bit)
    const int half = wv & 1;
    const int row  = half * 64 + rg * 4 + g;        // lane's final row

    // ---- weight store: one 64-VGPR block shared across wave roles ----
    union WU {
        h16x2 wp[4][16];    // wv0-3: rows half*64+rg*4+(j^g), cols c*32..+31
        h16x8 af[4][4];     // wv4,5: Wih1 MFMA A-frags
        h16x2 wo[16];       // wv6:   wout cols (lane&3)*32..+31
    } W;

    float bias = 0.f;
    h16x2 wx[3];
    if (wv < 4) {
        const float* Wsrc = (wv < 2) ? w_hh0 : w_hh1;
        #pragma unroll
        for (int j = 0; j < 4; ++j) {
            const float* rp = Wsrc + (half * 64 + rg * 4 + (j ^ g)) * HD + c * 32;
            #pragma unroll
            for (int t = 0; t < 16; ++t) {
                h16x2 w2 = { (_Float16)rp[2 * t], (_Float16)rp[2 * t + 1] };
                W.wp[j][t] = w2;
            }
        }
        if (wv < 2) {
            wx[0][0] = (_Float16)w_ih0[row * NF + 0];
            wx[0][1] = (_Float16)w_ih0[row * NF + 1];
            wx[1][0] = (_Float16)w_ih0[row * NF + 2];
            wx[1][1] = (_Float16)w_ih0[row * NF + 3];
            wx[2][0] = (_Float16)w_ih0[row * NF + 4];
            wx[2][1] = (_Float16)0.f;
            bias = b_ih0[row] + b_hh0[row];
        } else {
            bias = b_ih1[row] + b_hh1[row];
        }
    } else if (wv < 6) {
        // A-frag (16x16x32): lane holds A[m = mt*16 + (lane&15)]
        //                                [k = kt*32 + (lane>>4)*8 + j]
        const int m0 = (wv - 4) * 64;
        #pragma unroll
        for (int mt = 0; mt < 4; ++mt) {
            #pragma unroll
            for (int kt = 0; kt < 4; ++kt) {
                const float* rp = w_ih1 + (m0 + mt * 16 + (lane & 15)) * HD
                                + kt * 32 + (lane >> 4) * 8;
                h16x8 v;
                #pragma unroll
                for (int j = 0; j < 8; ++j) v[j] = (_Float16)rp[j];
                W.af[mt][kt] = v;
            }
        }
    } else if (wv == 6) {
        const int c4 = lane & 3;
        #pragma unroll
        for (int t = 0; t < 16; ++t) {
            h16x2 w2 = { (_Float16)w_out[c4 * 32 + 2 * t],
                         (_Float16)w_out[c4 * 32 + 2 * t + 1] };
            W.wo[t] = w2;
        }
    }
    const float bout = b_out[0];

    float hfin = 0.f;

    __syncthreads();

    // Tiled matvec: 4 ds_read_b128 (4 distinct addrs/wave, 2-way-free banks),
    // 4 rows x 16 fdot2, 2-level DPP tree -> full sum for row rg*4+g.
    auto matvec = [&](const _Float16* base) -> float {
        h16x8 hv[4];
        #pragma unroll
        for (int u2 = 0; u2 < 4; ++u2)
            hv[u2] = *(const h16x8*)(base + c * 32 + 8 * u2);
        float a[4] = {0.f, 0.f, 0.f, 0.f};
        #pragma unroll
        for (int j = 0; j < 4; ++j) {
            float aj = 0.f;
            #pragma unroll
            for (int t = 0; t < 16; ++t) {
                h16x2 hp = { hv[t >> 2][2 * (t & 3)], hv[t >> 2][2 * (t & 3) + 1] };
                aj = __builtin_amdgcn_fdot2(W.wp[j][t], hp, aj, false);
            }
            a[j] = aj;
        }
        // level1 (lane^1, g flips bit1): partner a[j^2] is my row's other half
        a[0] += dpp_mov<0xB1>(a[2]);
        a[1] += dpp_mov<0xB1>(a[3]);
        // level2 (lane^2, g flips bit0)
        a[0] += dpp_mov<0x4E>(a[1]);
        return a[0];        // row rg*4+g, all 128 cols
    };

    for (int s = 0; s < NSTEP; ++s) {
        if (wv < 2) {
            // h0[s] = relu(Whh0.h0[s-1] + Wih0.x[s] + b)
            if (s < TT) {
                float v = matvec(&ring0[(s + 31) & 31][0]) + bias;
                if (s < TIN) {
                    h16x8 xv = *(const h16x8*)(&x_h[s * 8]);
                    h16x2 xp0 = { xv[0], xv[1] };
                    h16x2 xp1 = { xv[2], xv[3] };
                    h16x2 xp2 = { xv[4], xv[5] };   // slot 5 is zero pad
                    float xc = __builtin_amdgcn_fdot2(wx[2], xp2, 0.f, false);
                    xc = __builtin_amdgcn_fdot2(wx[1], xp1, xc, false);
                    xc = __builtin_amdgcn_fdot2(wx[0], xp0, xc, false);
                    v += xc;
                }
                v = fmaxf(v, 0.f);
                ring0[s & 31][row] = (_Float16)v;
                if (s == TT - 1) hfin = v;
            }
        } else if (wv < 4) {
            // h1[u] = relu(Whh1.h1[u-1] + A[u] + b), u = s - 20
            if (s >= SK1) {
                const int u = s - SK1;
                float v = matvec(&ring1[(u + 31) & 31][0]);
                v = fmaxf(v + bias + A_f[u & 31][row], 0.f);
                ring1[u & 31][row] = (_Float16)v;
                if (u == TT - 1) hfin = v;
            }
        } else if (wv < 6) {
            // A burst: A[ub..ub+15] = Wih1 . h0[ub..ub+15], ub = s-17
            if (s >= 17 && s <= 1009 && ((s - 17) & 15) == 0) {
                const int ub = s - 17;
                const int un = ub + (lane & 15);    // this lane's column step
                h16x8 bf[4];    // B[k][n]: k = kt*32+(lane>>4)*8+j, n = lane&15
                #pragma unroll
                for (int kt = 0; kt < 4; ++kt)
                    bf[kt] = *(const h16x8*)(&ring0[un & 31]
                                             [kt * 32 + (lane >> 4) * 8]);
                #pragma unroll
                for (int mt = 0; mt < 4; ++mt) {
                    f32x4 acc = {0.f, 0.f, 0.f, 0.f};
                    #pragma unroll
                    for (int kt = 0; kt < 4; ++kt)
                        acc = __builtin_amdgcn_mfma_f32_16x16x32_f16(
                            W.af[mt][kt], bf[kt], acc, 0, 0, 0);
                    // C/D: col = lane&15 (step un), row = mt*16+(lane>>4)*4+reg
                    if (un < TT)
                        *(f32x4*)(&A_f[un & 31]
                                  [(wv - 4) * 64 + mt * 16 + (lane >> 4) * 4]) = acc;
                }
            }
        } else if (wv == 6) {
            // y burst: t = (s-37)+slot, slot = lane>>2; h1[t] ready (t+20 <= s-2)
            if (s >= 37 && s <= 821 && ((s - 37) & 15) == 0) {
                const int slot = lane >> 2;
                const int c4   = lane & 3;
                const int t    = (s - 37) + slot;
                const _Float16* rb = &ring1[t & 31][0] + c4 * 32;
                float z = 0.f;
                #pragma unroll
                for (int u2 = 0; u2 < 4; ++u2) {
                    h16x8 hv = *(const h16x8*)(rb + 8 * u2);
                    h16x2 hp0 = { hv[0], hv[1] };
                    h16x2 hp1 = { hv[2], hv[3] };
                    h16x2 hp2 = { hv[4], hv[5] };
                    h16x2 hp3 = { hv[6], hv[7] };
                    z = __builtin_amdgcn_fdot2(W.wo[4 * u2 + 0], hp0, z, false);
                    z = __builtin_amdgcn_fdot2(W.wo[4 * u2 + 1], hp1, z, false);
                    z = __builtin_amdgcn_fdot2(W.wo[4 * u2 + 2], hp2, z, false);
                    z = __builtin_amdgcn_fdot2(W.wo[4 * u2 + 3], hp3, z, false);
                }
                z += dpp_mov<0xB1>(z);    // xor1 (within quad)
                z += dpp_mov<0x4E>(z);    // xor2
                if (c4 == 0) y_lds[t] = 1.f / (1.f + expf(-(z + bout)));
            }
        }
        __syncthreads();
    }

    // ---- epilogue: single global dump ----
    for (int i = tid; i < TIN; i += 512)
        out[bb * TIN + i] = y_lds[i];
    if (wv < 2)
        out[TIN * BATCH + bb * HD + row] = hfin;
    else if (wv < 4)
        out[TIN * BATCH + BATCH * HD + bb * HD + row] = hfin;
}

extern "C" void kernel_launch(void* const* d_in, const int* in_sizes, int n_in,
                              void* d_out, int out_size, void* d_ws, size_t ws_size,
                              hipStream_t stream) {
    (void)in_sizes; (void)n_in; (void)d_ws; (void)ws_size; (void)out_size;
    rnn_dec<<<dim3(BATCH), dim3(512), 0, stream>>>(
        (const float*)d_in[0],  (const float*)d_in[1],
        (const float*)d_in[2],  (const float*)d_in[3],
        (const float*)d_in[4],  (const float*)d_in[5],
        (const float*)d_in[6],  (const float*)d_in[7],
        (const float*)d_in[8],  (const float*)d_in[9],
        (const float*)d_in[10], (const float*)d_in[11],
        (float*)d_out);
}